// Round 12
// baseline (113.188 us; speedup 1.0000x reference)
//
#include <hip/hip_runtime.h>

// LinearAttention collapsed:
//   dots[m,h] = sum_{d in head h} (X@Wk^T)*(X@Wv^T)   [dual GEMM, R2 core, compiler-scheduled]
//   qsum = X @ Wqs^T ; dotb = X @ CB^T                 [side GEMM, trailing blocks 512..767]
//   cum = cumsum_s((dots + dotb + dbc)*mask^2); coef = cum*(qsum+bqs)
//   out = coef @ WosT + bo ; state[b,h,:,:] = cum[b, S-1, h]

typedef __attribute__((ext_vector_type(4))) float f32x4;
typedef __attribute__((ext_vector_type(8))) short bf16x8;
typedef __attribute__((ext_vector_type(8))) unsigned short u16x8;
typedef unsigned int u32;

#define GLDS16(g, l)                                                            \
  __builtin_amdgcn_global_load_lds((const __attribute__((address_space(1))) u32*)(g), \
                                   (__attribute__((address_space(3))) u32*)(l), 16, 0, 0)
#define MFMA16(a, b, c) __builtin_amdgcn_mfma_f32_16x16x32_bf16(a, b, c, 0, 0, 0)

__device__ __forceinline__ unsigned short f2bf(float f) {
  union { float f; u32 u; } x; x.f = f;
  u32 r = (x.u + 0x7fffu + ((x.u >> 16) & 1u)) >> 16;
  return (unsigned short)r;
}

// ---------------- fused prep: Wk/Wv->bf16, weight sums, X->bf16 ----------------
__global__ void k_prep(const float* __restrict__ X, unsigned short* __restrict__ Xb,
                       const float* __restrict__ Wq, const float* __restrict__ bq,
                       const float* __restrict__ Wk, const float* __restrict__ bk,
                       const float* __restrict__ Wv, const float* __restrict__ bv,
                       const float* __restrict__ Wo,
                       unsigned short* __restrict__ Wkb, unsigned short* __restrict__ Wvb,
                       unsigned short* __restrict__ SWb, float* __restrict__ WosT,
                       float* __restrict__ scal) {
  int blk = blockIdx.x, t = threadIdx.x;
  if (blk < 2048) {                    // Wk/Wv convert
    const float* src = (blk < 1024) ? Wk : Wv;
    unsigned short* dst = (blk < 1024) ? Wkb : Wvb;
    size_t i = ((size_t)(blk & 1023) * 256 + t) * 4;
    f32x4 v = *(const f32x4*)(src + i);
    dst[i + 0] = f2bf(v.x); dst[i + 1] = f2bf(v.y);
    dst[i + 2] = f2bf(v.z); dst[i + 3] = f2bf(v.w);
  } else if (blk < 2241) {             // weight sums
    int b2 = blk - 2048;
    if (b2 < 128) {
      int o = b2 * 256 + t;
      int r = o >> 10, c = o & 1023;
      float s = 0.f;
      if (r < 16) {
        for (int d = 0; d < 64; ++d) s += Wq[(size_t)(r * 64 + d) * 1024 + c];
      } else {
        int h = r - 16;
        for (int d = 0; d < 64; ++d) {
          int j = h * 64 + d;
          s += bv[j] * Wk[(size_t)j * 1024 + c] + bk[j] * Wv[(size_t)j * 1024 + c];
        }
      }
      SWb[o] = f2bf(s);
    } else if (b2 < 192) {
      int o = (b2 - 128) * 256 + t;
      int h = o >> 10, j = o & 1023;
      float s = 0.f;
      for (int d = 0; d < 64; ++d) s += Wo[(size_t)j * 1024 + h * 64 + d];
      WosT[o] = s;
    } else {
      if (t < 16) {
        float s = 0.f;
        for (int d = 0; d < 64; ++d) s += bq[t * 64 + d];
        scal[t] = s;
      } else if (t < 32) {
        int h = t - 16;
        float s = 0.f;
        for (int d = 0; d < 64; ++d) s += bk[h * 64 + d] * bv[h * 64 + d];
        scal[t] = s;
      }
    }
  } else {                             // X convert
    size_t i = ((size_t)(blk - 2241) * 256 + t) * 8;
    f32x4 a = *(const f32x4*)(X + i);
    f32x4 b = *(const f32x4*)(X + i + 4);
    u16x8 o;
    o[0] = f2bf(a.x); o[1] = f2bf(a.y); o[2] = f2bf(a.z); o[3] = f2bf(a.w);
    o[4] = f2bf(b.x); o[5] = f2bf(b.y); o[6] = f2bf(b.z); o[7] = f2bf(b.w);
    *(u16x8*)(Xb + i) = o;
  }
}

// ---------------- dual GEMM (blocks 0..511) + side GEMM (blocks 512..767) ----------------
// Dual: BM=256, BN=128, BK=32, 8 waves (4M x 2N), 4 LDS buffers, prefetch depth 3,
// ONE barrier/tile with counted vmcnt(8); NO explicit lgkmcnt — compiler emits
// fine-grained lgkmcnt interleaving the 12 ds_reads with the 32 MFMAs (m97 evidence).
// Buffer (elems): A@0 (8192), Bk@8192 (4096), Bv@12288 (4096) = 16384; 4 bufs = 131072 B.
// bf16 rows 64B = 4x16B units; swizzle key (row>>1)&3 on source and read (0-conflict).
// Side: X @ SWb^T (N=32), K-split 4, 256 blocks backfilling as dual blocks drain.
#define NT 32
#define BUFS 16384
__global__ __launch_bounds__(512, 2) void k_dualgemm(
    const unsigned short* __restrict__ Xb,
    const unsigned short* __restrict__ Wkb,
    const unsigned short* __restrict__ Wvb,
    const unsigned short* __restrict__ SWb,
    float* __restrict__ dotsT, float* __restrict__ side4) {
  extern __shared__ __align__(16) unsigned short lds[];
  int orig = blockIdx.x;
  int tid = threadIdx.x, wid = tid >> 6, lane = tid & 63;
  int fr = lane & 15, fg = lane >> 4;

  if (orig >= 512) {   // ---------------- side path ----------------
    int unit = orig - 512;
    int rowblk = unit >> 2, ks = unit & 3;
    int row0 = rowblk << 8;
    unsigned short* As = lds;           // 8192 elems
    unsigned short* Ss = lds + 8192;    // 1024 elems
    int uA0 = tid, uA1 = tid + 512;
    const unsigned short* sA0 = Xb + (size_t)(row0 + (uA0 >> 2)) * 1024 + ks * 256 + (((uA0 & 3) ^ ((uA0 >> 3) & 3)) << 3);
    const unsigned short* sA1 = Xb + (size_t)(row0 + (uA1 >> 2)) * 1024 + ks * 256 + (((uA1 & 3) ^ ((uA1 >> 3) & 3)) << 3);
    int uS = ((wid & 1) << 6) + lane;
    const unsigned short* sS = SWb + (size_t)(uS >> 2) * 1024 + ks * 256 + (((uS & 3) ^ ((uS >> 3) & 3)) << 3);
    int xsw = (fg ^ ((fr >> 1) & 3)) << 3;
    int aro = (wid * 32 + fr) * 32 + xsw;
    int sro = fr * 32 + xsw;
    f32x4 acc[2][2] = {{0}};
    for (int t = 0; t < 8; ++t) {
      int ko = t << 5;
      __syncthreads();
      GLDS16(sA0 + ko, As + (wid << 9));
      GLDS16(sA1 + ko, As + 4096 + (wid << 9));
      if (wid < 2) GLDS16(sS + ko, Ss + ((wid & 1) << 9));
      asm volatile("s_waitcnt vmcnt(0)" ::: "memory");
      __syncthreads();
      bf16x8 a0 = *(const bf16x8*)(As + aro);
      bf16x8 a1 = *(const bf16x8*)(As + aro + 512);
      bf16x8 s0 = *(const bf16x8*)(Ss + sro);
      bf16x8 s1 = *(const bf16x8*)(Ss + sro + 512);
      acc[0][0] = MFMA16(a0, s0, acc[0][0]);
      acc[0][1] = MFMA16(a0, s1, acc[0][1]);
      acc[1][0] = MFMA16(a1, s0, acc[1][0]);
      acc[1][1] = MFMA16(a1, s1, acc[1][1]);
    }
    size_t mbase = row0 + wid * 32;
#pragma unroll
    for (int mi = 0; mi < 2; ++mi)
#pragma unroll
      for (int ni = 0; ni < 2; ++ni)
#pragma unroll
        for (int q = 0; q < 4; ++q)
          side4[(size_t)((ni * 4 + ks) * 16 + fr) * 16384 + mbase + mi * 16 + fg * 4 + q] =
              acc[mi][ni][q];
    return;
  }

  // ---------------- dual path ----------------
  int wg = (orig & 7) * 64 + (orig >> 3);    // XCD-chunked swizzle (512 % 8 == 0)
  int bx = wg & 7, by = wg >> 3;
  int row0 = by << 8, col0 = bx << 7;
  int wrM = wid >> 1, wcN = wid & 1;

  int uA0 = tid, uA1 = tid + 512;
  const unsigned short* sA0 = Xb + (size_t)(row0 + (uA0 >> 2)) * 1024 + (((uA0 & 3) ^ ((uA0 >> 3) & 3)) << 3);
  const unsigned short* sA1 = Xb + (size_t)(row0 + (uA1 >> 2)) * 1024 + (((uA1 & 3) ^ ((uA1 >> 3) & 3)) << 3);
  const unsigned short* sK  = Wkb + (size_t)(col0 + (tid >> 2)) * 1024 + (((tid & 3) ^ ((tid >> 3) & 3)) << 3);
  const unsigned short* sV  = Wvb + (size_t)(col0 + (tid >> 2)) * 1024 + (((tid & 3) ^ ((tid >> 3) & 3)) << 3);
  int dA0 = wid << 9, dA1 = 4096 + (wid << 9);
  int dK = 8192 + (wid << 9), dV = 12288 + (wid << 9);

  int xsw = (fg ^ ((fr >> 1) & 3)) << 3;
  int aro = (wrM * 64 + fr) * 32 + xsw;   // + mi*512
  int bro = (wcN * 64 + fr) * 32 + xsw;   // + ni*512 (+8192 Bk, +12288 Bv)

  f32x4 ck[4][4] = {{0}}, cv[4][4] = {{0}};

  // prologue: stage tiles 0,1,2
#pragma unroll
  for (int p = 0; p < 3; ++p) {
    int bb = p * BUFS, ko = p * 32;
    GLDS16(sA0 + ko, lds + bb + dA0);
    GLDS16(sK + ko, lds + bb + dK);
    GLDS16(sA1 + ko, lds + bb + dA1);
    GLDS16(sV + ko, lds + bb + dV);
  }

  for (int t = 0; t < NT; ++t) {
    int rb = (t & 3) * BUFS;
    if (t < NT - 3) { asm volatile("s_waitcnt vmcnt(8)" ::: "memory"); }
    else            { asm volatile("s_waitcnt vmcnt(0)" ::: "memory"); }
    __builtin_amdgcn_s_barrier();

    bf16x8 a[4], bk[4], bv[4];
#pragma unroll
    for (int mi = 0; mi < 4; ++mi) a[mi] = *(const bf16x8*)(lds + rb + aro + mi * 512);
#pragma unroll
    for (int ni = 0; ni < 2; ++ni) {
      bk[ni] = *(const bf16x8*)(lds + rb + 8192 + bro + ni * 512);
      bv[ni] = *(const bf16x8*)(lds + rb + 12288 + bro + ni * 512);
    }
    int t3 = t + 3;
    int bb = (t3 & 3) * BUFS, ko = t3 << 5;
    if (t3 < NT) {
      GLDS16(sA0 + ko, lds + bb + dA0);
      GLDS16(sK + ko, lds + bb + dK);
    }
    __builtin_amdgcn_s_setprio(1);
#pragma unroll
    for (int mi = 0; mi < 4; ++mi)
#pragma unroll
      for (int ni = 0; ni < 2; ++ni) {
        ck[mi][ni] = MFMA16(a[mi], bk[ni], ck[mi][ni]);
        cv[mi][ni] = MFMA16(a[mi], bv[ni], cv[mi][ni]);
      }
    __builtin_amdgcn_s_setprio(0);

#pragma unroll
    for (int ni = 2; ni < 4; ++ni) {
      bk[ni] = *(const bf16x8*)(lds + rb + 8192 + bro + ni * 512);
      bv[ni] = *(const bf16x8*)(lds + rb + 12288 + bro + ni * 512);
    }
    if (t3 < NT) {
      GLDS16(sA1 + ko, lds + bb + dA1);
      GLDS16(sV + ko, lds + bb + dV);
    }
    __builtin_amdgcn_s_setprio(1);
#pragma unroll
    for (int mi = 0; mi < 4; ++mi)
#pragma unroll
      for (int ni = 2; ni < 4; ++ni) {
        ck[mi][ni] = MFMA16(a[mi], bk[ni], ck[mi][ni]);
        cv[mi][ni] = MFMA16(a[mi], bv[ni], cv[mi][ni]);
      }
    __builtin_amdgcn_s_setprio(0);
  }

  // epilogue: dots = per-head sum over 64 cols of ck*cv
  float part[4][4];
#pragma unroll
  for (int mi = 0; mi < 4; ++mi)
#pragma unroll
    for (int q = 0; q < 4; ++q) {
      float s = 0.f;
#pragma unroll
      for (int ni = 0; ni < 4; ++ni) s += ck[mi][ni][q] * cv[mi][ni][q];
      part[mi][q] = s;
    }
#pragma unroll
  for (int r = 0; r < 4; ++r) {
#pragma unroll
    for (int mi = 0; mi < 4; ++mi)
#pragma unroll
      for (int q = 0; q < 4; ++q)
        part[mi][q] += __shfl_xor(part[mi][q], 1 << r, 64);
  }
  int h = bx * 2 + wcN;
  if (fr == 0) {
#pragma unroll
    for (int mi = 0; mi < 4; ++mi)
#pragma unroll
      for (int q = 0; q < 4; ++q)
        dotsT[(size_t)h * 16384 + row0 + wrM * 64 + mi * 16 + fg * 4 + q] = part[mi][q];
  }
}

// ---------------- cumsum + coef + state ----------------
__global__ void k_cumsum(const float* __restrict__ dotsT, const float* __restrict__ side4,
                         const float* __restrict__ scal, const float* __restrict__ mask,
                         float* __restrict__ coef, float* __restrict__ state) {
  __shared__ float csum[256];
  int b = blockIdx.x >> 4, h = blockIdx.x & 15;
  int t = threadIdx.x;
  float bqs = scal[h], dbc = scal[16 + h];
  size_t m0 = (size_t)b * 4096;
  const size_t KSS = (size_t)16 * 16384;
  const float* dro = dotsT + (size_t)h * 16384 + m0;
  const float* qb = side4 + (size_t)h * 16384 + m0;
  const float* db = side4 + 4 * KSS + (size_t)h * 16384 + m0;
  const float* mko = mask + m0;
  float loc[16], run = 0.f;
  int s0 = t * 16;
#pragma unroll
  for (int i = 0; i < 16; ++i) {
    int ii = s0 + i;
    float mk = mko[ii];
    float dball = db[ii] + db[ii + KSS] + db[ii + 2 * KSS] + db[ii + 3 * KSS];
    float d = (dro[ii] + dball + dbc) * mk * mk;
    run += d;
    loc[i] = run;
  }
  csum[t] = run;
  __syncthreads();
  for (int off = 1; off < 256; off <<= 1) {
    float v = (t >= off) ? csum[t - off] : 0.f;
    __syncthreads();
    csum[t] += v;
    __syncthreads();
  }
  float prefix = csum[t] - run;
#pragma unroll
  for (int i = 0; i < 16; ++i) {
    int ii = s0 + i;
    float cum = prefix + loc[i];
    float qs = qb[ii] + qb[ii + KSS] + qb[ii + 2 * KSS] + qb[ii + 3 * KSS];
    coef[(m0 + ii) * 16 + h] = cum * (qs + bqs);
  }
  float total = csum[255];
  float* sp = state + (size_t)(b * 16 + h) * 4096;
  for (int i = t; i < 4096; i += 256) sp[i] = total;
}

// ---------------- output GEMM: out = coef(16384x16) @ WosT(16x1024) + bo ----------------
__global__ __launch_bounds__(256) void k_outgemm(const float* __restrict__ coef,
                                                 const float* __restrict__ WosT,
                                                 const float* __restrict__ bo,
                                                 float* __restrict__ out) {
  int t = threadIdx.x;
  int j0 = t * 4;
  f32x4 w4[16];
#pragma unroll
  for (int hh = 0; hh < 16; ++hh) w4[hh] = *(const f32x4*)&WosT[hh * 1024 + j0];
  f32x4 bov = *(const f32x4*)&bo[j0];
  size_t m0 = (size_t)blockIdx.x * 32;
  for (int mi = 0; mi < 32; ++mi) {
    size_t m = m0 + mi;
    const float* cm = &coef[m * 16];
    f32x4 acc = bov;
#pragma unroll
    for (int hh = 0; hh < 16; ++hh) acc += w4[hh] * cm[hh];
    *(f32x4*)&out[m * 1024 + j0] = acc;
  }
}

extern "C" void kernel_launch(void* const* d_in, const int* in_sizes, int n_in,
                              void* d_out, int out_size, void* d_ws, size_t ws_size,
                              hipStream_t stream) {
  const float* X    = (const float*)d_in[0];
  const float* mask = (const float*)d_in[1];
  const float* Wq   = (const float*)d_in[2];
  const float* bq   = (const float*)d_in[3];
  const float* Wk   = (const float*)d_in[4];
  const float* bk   = (const float*)d_in[5];
  const float* Wv   = (const float*)d_in[6];
  const float* bv   = (const float*)d_in[7];
  const float* Wo   = (const float*)d_in[8];
  const float* bo   = (const float*)d_in[9];
  float* out   = (float*)d_out;
  float* state = out + (size_t)16384 * 1024;

  char* w = (char*)d_ws;
  unsigned short* Xb  = (unsigned short*)w; w += (size_t)16384 * 1024 * 2;
  unsigned short* Wkb = (unsigned short*)w; w += (size_t)1024 * 1024 * 2;
  unsigned short* Wvb = (unsigned short*)w; w += (size_t)1024 * 1024 * 2;
  unsigned short* SWb = (unsigned short*)w; w += (size_t)32 * 1024 * 2;
  float* WosT  = (float*)w; w += (size_t)16 * 1024 * 4;
  float* scal  = (float*)w; w += 256;
  float* dotsT = (float*)w; w += (size_t)16 * 16384 * 4;
  float* side4 = (float*)w; w += (size_t)8 * 16 * 16384 * 4;
  float* coef  = (float*)w; w += (size_t)16384 * 16 * 4;

  (void)hipFuncSetAttribute((const void*)k_dualgemm,
                            hipFuncAttributeMaxDynamicSharedMemorySize, 131072);

  hipLaunchKernelGGL(k_prep,     dim3(10433), dim3(256), 0, stream,
                     X, Xb, Wq, bq, Wk, bk, Wv, bv, Wo, Wkb, Wvb, SWb, WosT, scal);
  hipLaunchKernelGGL(k_dualgemm, dim3(768),  dim3(512), 131072, stream, Xb, Wkb, Wvb, SWb,
                     dotsT, side4);
  hipLaunchKernelGGL(k_cumsum,   dim3(64),   dim3(256), 0, stream, dotsT, side4, scal,
                     mask, coef, state);
  hipLaunchKernelGGL(k_outgemm,  dim3(512),  dim3(256), 0, stream, coef, WosT, bo, out);
}